// Round 1
// baseline (334.693 us; speedup 1.0000x reference)
//
#include <hip/hip_runtime.h>
#include <hip/hip_bf16.h>

// Problem: x[16,2048,1024] f32; qk = x@Wqk^T + bqk; v = x@Wv^T + bv (D=128)
// out = softmax(qk@qk^T) @ v   -> [16,2048,128] f32
//
// ws layout (bytes): qk_h 8M | qk_l 8M | vT 8M | Wqk_h 256K | Wqk_l 256K | Wv_h 256K  (~26 MB)

typedef __bf16 bf16x8 __attribute__((ext_vector_type(8)));
typedef float f32x4 __attribute__((ext_vector_type(4)));
typedef unsigned short us4 __attribute__((ext_vector_type(4)));

static __device__ __forceinline__ unsigned short f2bf(float f) {
  unsigned u = __builtin_bit_cast(unsigned, f);
  u += 0x7fffu + ((u >> 16) & 1u);          // RNE
  return (unsigned short)(u >> 16);
}
static __device__ __forceinline__ float bf2f(unsigned short h) {
  unsigned u = ((unsigned)h) << 16;
  return __builtin_bit_cast(float, u);
}
static __device__ __forceinline__ f32x4 mfma16(bf16x8 a, bf16x8 b, f32x4 c) {
  return __builtin_amdgcn_mfma_f32_16x16x32_bf16(a, b, c, 0, 0, 0);
}
static __device__ __forceinline__ void gload16(const void* g, void* l) {
  __builtin_amdgcn_global_load_lds(
      (const __attribute__((address_space(1))) unsigned*)g,
      (__attribute__((address_space(3))) unsigned*)l, 16, 0, 0);
}

// ---------------- kernel 1: weight prep (fp32 -> bf16 hi/lo) ----------------
__global__ void kprep(const float* __restrict__ wqk, const float* __restrict__ wv,
                      unsigned short* __restrict__ Wqk_h, unsigned short* __restrict__ Wqk_l,
                      unsigned short* __restrict__ Wv_h) {
  int i = blockIdx.x * 256 + threadIdx.x;   // grid covers exactly 128*1024
  float f = wqk[i];
  unsigned short h = f2bf(f);
  Wqk_h[i] = h;
  Wqk_l[i] = f2bf(f - bf2f(h));
  Wv_h[i] = f2bf(wv[i]);
}

// ---------------- kernel 2: projections ----------------
// block = 64 rows of x, 4 waves; wave w owns rows w*16..w*16+15, all 256 out cols
// qk (cols 0..127): hi/lo 3-term MFMA; v (cols 128..255): plain bf16
__launch_bounds__(256, 2)
__global__ void kproj(const float* __restrict__ x,
                      const unsigned short* __restrict__ Wqk_h,
                      const unsigned short* __restrict__ Wqk_l,
                      const unsigned short* __restrict__ Wv_h,
                      const float* __restrict__ bqk, const float* __restrict__ bv,
                      unsigned short* __restrict__ qk_h, unsigned short* __restrict__ qk_l,
                      unsigned short* __restrict__ vT) {
  __shared__ unsigned short smem[128 * 68];       // 17408 B: Xh/Xl (5120 shorts) then reused for v-transpose
  unsigned short* Xh = smem;                      // [64][40]  (pad 40: 2-way banks only)
  unsigned short* Xl = smem + 64 * 40;            // [64][40]
  const int t = threadIdx.x;
  const int lane = t & 63;
  const int w = t >> 6;
  const int r_lo = lane & 15;
  const int g = lane >> 4;
  const long mb = (long)blockIdx.x * 64;

  f32x4 zero = {0.f, 0.f, 0.f, 0.f};
  f32x4 acc[16];
#pragma unroll
  for (int i = 0; i < 16; ++i) acc[i] = zero;

  for (int ks = 0; ks < 32; ++ks) {
    __syncthreads();
    // stage x tile [64][32] fp32 -> hi/lo bf16 in LDS
#pragma unroll
    for (int it = 0; it < 2; ++it) {
      int c = t + 256 * it;
      int row = c >> 3;
      int ko = (c & 7) * 4;
      const float4 xv = *(const float4*)(x + (mb + row) * 1024 + ks * 32 + ko);
      float fv0 = xv.x, fv1 = xv.y, fv2 = xv.z, fv3 = xv.w;
      us4 hv, lv;
      unsigned short h;
      h = f2bf(fv0); hv[0] = h; lv[0] = f2bf(fv0 - bf2f(h));
      h = f2bf(fv1); hv[1] = h; lv[1] = f2bf(fv1 - bf2f(h));
      h = f2bf(fv2); hv[2] = h; lv[2] = f2bf(fv2 - bf2f(h));
      h = f2bf(fv3); hv[3] = h; lv[3] = f2bf(fv3 - bf2f(h));
      *(us4*)(Xh + row * 40 + ko) = hv;
      *(us4*)(Xl + row * 40 + ko) = lv;
    }
    __syncthreads();
    const int arow = w * 16 + r_lo;
    bf16x8 Ah = *(const bf16x8*)(Xh + arow * 40 + g * 8);
    bf16x8 Al = *(const bf16x8*)(Xl + arow * 40 + g * 8);
    const int wko = ks * 32 + g * 8;
#pragma unroll
    for (int oc = 0; oc < 8; ++oc) {
      int o = oc * 16 + r_lo;
      bf16x8 Bh = *(const bf16x8*)(Wqk_h + o * 1024 + wko);
      bf16x8 Bl = *(const bf16x8*)(Wqk_l + o * 1024 + wko);
      acc[oc] = mfma16(Ah, Bh, acc[oc]);
      acc[oc] = mfma16(Al, Bh, acc[oc]);
      acc[oc] = mfma16(Ah, Bl, acc[oc]);
    }
#pragma unroll
    for (int oc = 0; oc < 8; ++oc) {
      int o = oc * 16 + r_lo;
      bf16x8 Bv = *(const bf16x8*)(Wv_h + o * 1024 + wko);
      acc[8 + oc] = mfma16(Ah, Bv, acc[8 + oc]);
    }
  }
  // ---- epilogue: qk -> hi/lo store [m][128] (D layout: row=g*4+r, col=lane&15) ----
#pragma unroll
  for (int oc = 0; oc < 8; ++oc) {
#pragma unroll
    for (int r = 0; r < 4; ++r) {
      long m = mb + w * 16 + g * 4 + r;
      int o = oc * 16 + r_lo;
      float val = acc[oc][r] + bqk[o];
      unsigned short h = f2bf(val);
      qk_h[m * 128 + o] = h;
      qk_l[m * 128 + o] = f2bf(val - bf2f(h));
    }
  }
  // ---- epilogue: v -> transpose in LDS, store vT[b][d][n] coalesced ----
  __syncthreads();
#pragma unroll
  for (int oc = 0; oc < 8; ++oc) {
#pragma unroll
    for (int r = 0; r < 4; ++r) {
      int d = oc * 16 + r_lo;
      int ml = w * 16 + g * 4 + r;
      smem[d * 68 + ml] = f2bf(acc[8 + oc][r] + bv[d]);   // [128][68]
    }
  }
  __syncthreads();
  const long bb = mb >> 11;        // batch
  const long n0 = mb & 2047;       // n within batch
#pragma unroll
  for (int it = 0; it < 8; ++it) {
    int d = (t >> 4) + 16 * it;
    int m0 = (t & 15) * 4;
    us4 vv = *(const us4*)(smem + d * 68 + m0);
    *(us4*)(vT + (bb * 128 + d) * 2048 + n0 + m0) = vv;
  }
}

// ---------------- kernel 3: flash attention ----------------
// block = 64 q rows of one batch, 4 waves x 16 q rows; KV tiles of 64
#define KH_OFF 0
#define KL_OFF 16384
#define VT_OFF 32768
#define P_OFF  49152
#define SMEM_B (49152 + 4 * 2304)

__launch_bounds__(256, 2)
__global__ void kattn(const unsigned short* __restrict__ qk_h,
                      const unsigned short* __restrict__ qk_l,
                      const unsigned short* __restrict__ vT,
                      float* __restrict__ out) {
  __shared__ char smem[SMEM_B];
  const int t = threadIdx.x;
  const int lane = t & 63;
  const int w = t >> 6;
  const int r_lo = lane & 15;
  const int g = lane >> 4;
  const long b = blockIdx.x >> 5;
  const int qt = blockIdx.x & 31;
  const long qrow = b * 2048 + qt * 64 + w * 16 + r_lo;

  // Q fragments (hi/lo), row = lane&15, contiguous k
  bf16x8 Qh[4], Ql[4];
#pragma unroll
  for (int kk = 0; kk < 4; ++kk) {
    Qh[kk] = *(const bf16x8*)(qk_h + qrow * 128 + kk * 32 + g * 8);
    Ql[kk] = *(const bf16x8*)(qk_l + qrow * 128 + kk * 32 + g * 8);
  }

  f32x4 zero = {0.f, 0.f, 0.f, 0.f};
  f32x4 Oa[8];
#pragma unroll
  for (int i = 0; i < 8; ++i) Oa[i] = zero;
  float mrun = -1e30f, lrun = 0.f;

  unsigned short* P = (unsigned short*)(smem + P_OFF + w * 2304);  // per-wave [16][72]

  for (int jt = 0; jt < 32; ++jt) {
    const long jb = b * 2048 + (long)jt * 64;  // qk row base of kv tile
    const int jn = jt * 64;                    // n base within batch (for vT)
    __syncthreads();
    // ---- stage K hi/lo (XOR-swizzled via pre-swizzled global src) + V^T tile ----
#pragma unroll
    for (int c = 0; c < 4; ++c) {
      int slot = w * 4 + c;                            // 0..15, wave-uniform
      {
        int row = slot * 4 + (lane >> 4);              // 0..63
        int chunk = (lane & 15) ^ (row & 7);
        gload16((const char*)(qk_h + (jb + row) * 128) + chunk * 16,
                smem + KH_OFF + slot * 1024);
        gload16((const char*)(qk_l + (jb + row) * 128) + chunk * 16,
                smem + KL_OFF + slot * 1024);
      }
      {
        int row = slot * 8 + (lane >> 3);              // d: 0..127
        int chunk = (lane & 7) ^ (row & 7);
        gload16((const char*)(vT + (b * 128 + row) * 2048 + jn) + chunk * 16,
                smem + VT_OFF + slot * 1024);
      }
    }
    asm volatile("s_waitcnt vmcnt(0)" ::: "memory");
    __syncthreads();

    // ---- S^T[j][q] = K . Q^T  (hi*hi + hi*lo + lo*hi) ----
    f32x4 sAcc[4];
#pragma unroll
    for (int jc = 0; jc < 4; ++jc) sAcc[jc] = zero;
#pragma unroll
    for (int jc = 0; jc < 4; ++jc) {
      int krow = jc * 16 + r_lo;
#pragma unroll
      for (int kk = 0; kk < 4; ++kk) {
        int chunk = (kk * 4 + g) ^ (krow & 7);
        bf16x8 Kh = *(const bf16x8*)(smem + KH_OFF + krow * 256 + chunk * 16);
        bf16x8 Kl = *(const bf16x8*)(smem + KL_OFF + krow * 256 + chunk * 16);
        sAcc[jc] = mfma16(Kh, Qh[kk], sAcc[jc]);
        sAcc[jc] = mfma16(Kh, Ql[kk], sAcc[jc]);
        sAcc[jc] = mfma16(Kl, Qh[kk], sAcc[jc]);
      }
    }

    // ---- online softmax; this lane's q = r_lo; j = jc*16 + g*4 + r ----
    float mt = -1e30f;
#pragma unroll
    for (int jc = 0; jc < 4; ++jc)
#pragma unroll
      for (int r = 0; r < 4; ++r) mt = fmaxf(mt, sAcc[jc][r]);
    mt = fmaxf(mt, __shfl_xor(mt, 16));
    mt = fmaxf(mt, __shfl_xor(mt, 32));
    float mnew = fmaxf(mrun, mt);
    float alpha = __expf(mrun - mnew);
    float ls = 0.f;
#pragma unroll
    for (int jc = 0; jc < 4; ++jc) {
      us4 pk;
#pragma unroll
      for (int r = 0; r < 4; ++r) {
        float p = __expf(sAcc[jc][r] - mnew);
        unsigned short pb = f2bf(p);
        pk[r] = pb;
        ls += bf2f(pb);                       // denominator consistent with bf16 numerator
      }
      *(us4*)(P + r_lo * 72 + jc * 16 + g * 4) = pk;   // P[q][j] packed b64
    }
    ls += __shfl_xor(ls, 16);
    ls += __shfl_xor(ls, 32);
    lrun = lrun * alpha + ls;
    mrun = mnew;
    // rescale O: O rows are q' = g*4+r -> fetch that row's alpha from lane q'
#pragma unroll
    for (int r = 0; r < 4; ++r) {
      float ar = __shfl(alpha, g * 4 + r);
#pragma unroll
      for (int dc = 0; dc < 8; ++dc) Oa[dc][r] *= ar;
    }

    // ---- PV: O[q][d] += P[q][j] * V[j][d] ----
#pragma unroll
    for (int ks = 0; ks < 2; ++ks) {
      bf16x8 Pa = *(const bf16x8*)(P + r_lo * 72 + ks * 32 + g * 8);
#pragma unroll
      for (int dc = 0; dc < 8; ++dc) {
        int d = dc * 16 + r_lo;
        int chunk = (ks * 4 + g) ^ (d & 7);
        bf16x8 Vb = *(const bf16x8*)(smem + VT_OFF + d * 128 + chunk * 16);
        Oa[dc] = mfma16(Pa, Vb, Oa[dc]);
      }
    }
  }

  // ---- epilogue: normalize and store fp32 ----
#pragma unroll
  for (int r = 0; r < 4; ++r) {
    float li = 1.f / __shfl(lrun, g * 4 + r);
    long orow = b * 2048 + qt * 64 + w * 16 + g * 4 + r;
#pragma unroll
    for (int dc = 0; dc < 8; ++dc) {
      out[orow * 128 + dc * 16 + r_lo] = Oa[dc][r] * li;
    }
  }
}

extern "C" void kernel_launch(void* const* d_in, const int* in_sizes, int n_in,
                              void* d_out, int out_size, void* d_ws, size_t ws_size,
                              hipStream_t stream) {
  const float* x     = (const float*)d_in[0];
  const float* wqk_w = (const float*)d_in[1];
  const float* wqk_b = (const float*)d_in[2];
  const float* wv_w  = (const float*)d_in[3];
  const float* wv_b  = (const float*)d_in[4];
  float* out = (float*)d_out;

  unsigned short* qk_h  = (unsigned short*)d_ws;             // 32768*128
  unsigned short* qk_l  = qk_h + 32768 * 128;
  unsigned short* vT    = qk_l + 32768 * 128;                // [16][128][2048]
  unsigned short* Wqk_h = vT + 16 * 128 * 2048;              // [128][1024]
  unsigned short* Wqk_l = Wqk_h + 128 * 1024;
  unsigned short* Wv_h  = Wqk_l + 128 * 1024;

  hipLaunchKernelGGL(kprep, dim3(512), dim3(256), 0, stream,
                     wqk_w, wv_w, Wqk_h, Wqk_l, Wv_h);
  hipLaunchKernelGGL(kproj, dim3(512), dim3(256), 0, stream,
                     x, Wqk_h, Wqk_l, Wv_h, wqk_b, wv_b, qk_h, qk_l, vT);
  hipLaunchKernelGGL(kattn, dim3(512), dim3(256), 0, stream,
                     qk_h, qk_l, vT, out);
}

// Round 2
// 144.674 us; speedup vs baseline: 2.3134x; 2.3134x over previous
//
#include <hip/hip_runtime.h>
#include <hip/hip_bf16.h>

// Problem: x[16,2048,1024] f32; qk = x@Wqk^T + bqk; v = x@Wv^T + bv (D=128)
// out = softmax(qk@qk^T) @ v   -> [16,2048,128] f32
//
// ws layout: qk_h 8M | qk_l 8M | vT 8M | Wqk_h 256K | Wqk_l 256K | Wv_h 256K

typedef __bf16 bf16x8 __attribute__((ext_vector_type(8)));
typedef float f32x4 __attribute__((ext_vector_type(4)));
typedef unsigned short us4 __attribute__((ext_vector_type(4)));
typedef unsigned short us8 __attribute__((ext_vector_type(8)));

static __device__ __forceinline__ unsigned short f2bf(float f) {
  unsigned u = __builtin_bit_cast(unsigned, f);
  u += 0x7fffu + ((u >> 16) & 1u);          // RNE
  return (unsigned short)(u >> 16);
}
static __device__ __forceinline__ float bf2f(unsigned short h) {
  unsigned u = ((unsigned)h) << 16;
  return __builtin_bit_cast(float, u);
}
static __device__ __forceinline__ f32x4 mfma16(bf16x8 a, bf16x8 b, f32x4 c) {
  return __builtin_amdgcn_mfma_f32_16x16x32_bf16(a, b, c, 0, 0, 0);
}
static __device__ __forceinline__ void gload16(const void* g, void* l) {
  __builtin_amdgcn_global_load_lds(
      (const __attribute__((address_space(1))) unsigned*)g,
      (__attribute__((address_space(3))) unsigned*)l, 16, 0, 0);
}

// ---------------- kernel 1: weight prep (fp32 -> bf16 hi/lo) ----------------
__global__ void kprep(const float* __restrict__ wqk, const float* __restrict__ wv,
                      unsigned short* __restrict__ Wqk_h, unsigned short* __restrict__ Wqk_l,
                      unsigned short* __restrict__ Wv_h) {
  int i = blockIdx.x * 256 + threadIdx.x;   // grid covers exactly 128*1024
  float f = wqk[i];
  unsigned short h = f2bf(f);
  Wqk_h[i] = h;
  Wqk_l[i] = f2bf(f - bf2f(h));
  Wv_h[i] = f2bf(wv[i]);
}

// ---------------- kernel 2: projections (v2: LDS-staged weights, dbuf) -------
// block = 64 rows, 4 waves COLUMN-partitioned: wave w owns output tiles
// {qk: 2w, 2w+1} and {v: cols w*32..w*32+31}; all 64 rows.
// LDS per buffer (32 KB): Xh 4K | Xl 4K | Wh 8K | Wl 8K | Wv 8K, all [row][32] bf16
// (64 B rows -> fragment ds_read_b128 lands 8 lanes/bank-start = BW floor, no swizzle)
#define XH_OFF 0
#define XL_OFF 4096
#define WH_OFF 8192
#define WL_OFF 16384
#define WV_OFF 24576
#define BUF_B  32768

__launch_bounds__(256, 2)
__global__ void kproj(const float* __restrict__ x,
                      const unsigned short* __restrict__ Wqk_h,
                      const unsigned short* __restrict__ Wqk_l,
                      const unsigned short* __restrict__ Wv_h,
                      const float* __restrict__ bqk, const float* __restrict__ bv,
                      unsigned short* __restrict__ qk_h, unsigned short* __restrict__ qk_l,
                      unsigned short* __restrict__ vT) {
  extern __shared__ char smem[];            // 2 * BUF_B = 64 KB (dynamic)
  const int t = threadIdx.x;
  const int lane = t & 63;
  const int w = t >> 6;
  const int r_lo = lane & 15;
  const int g = lane >> 4;
  const long mb = (long)blockIdx.x * 64;

  // X staging role: thread handles row xrow, k-chunk xkc (8 consecutive k)
  const int xrow = t >> 2;
  const int xkc = t & 3;
  // W staging role (per wave): slots 2w, 2w+1 of each W matrix (16 rows/slot)
  const int wgrow = (lane >> 2);            // row within slot
  const int wgcol = (lane & 3) * 8;         // k offset (shorts) within 32

  f32x4 zero = {0.f, 0.f, 0.f, 0.f};
  f32x4 acc[4][4];                          // [rowblock][tile: qk0,qk1,v0,v1]
#pragma unroll
  for (int i = 0; i < 4; ++i)
#pragma unroll
    for (int j = 0; j < 4; ++j) acc[i][j] = zero;

  // ---- prologue: stage ks=0 into buf0 ----
  {
    char* buf = smem;
#pragma unroll
    for (int i = 0; i < 2; ++i) {
      int s = 2 * w + i;
      long goff = (long)(s * 16 + wgrow) * 1024 + wgcol;   // shorts
      gload16(Wqk_h + goff, buf + WH_OFF + s * 1024);
      gload16(Wqk_l + goff, buf + WL_OFF + s * 1024);
      gload16(Wv_h + goff, buf + WV_OFF + s * 1024);
    }
    const float* px = x + (mb + xrow) * 1024 + xkc * 8;
    float4 xa = *(const float4*)px;
    float4 xb = *(const float4*)(px + 4);
    us8 hv, lv;
#pragma unroll
    for (int i = 0; i < 4; ++i) {
      float fa = (i == 0) ? xa.x : (i == 1) ? xa.y : (i == 2) ? xa.z : xa.w;
      float fb = (i == 0) ? xb.x : (i == 1) ? xb.y : (i == 2) ? xb.z : xb.w;
      unsigned short h;
      h = f2bf(fa); hv[i] = h; lv[i] = f2bf(fa - bf2f(h));
      h = f2bf(fb); hv[4 + i] = h; lv[4 + i] = f2bf(fb - bf2f(h));
    }
    *(us8*)(buf + XH_OFF + xrow * 64 + xkc * 16) = hv;
    *(us8*)(buf + XL_OFF + xrow * 64 + xkc * 16) = lv;
  }
  __syncthreads();

  // ---- main loop ----
  for (int ks = 0; ks < 32; ++ks) {
    char* cur = smem + (ks & 1) * BUF_B;
    char* nxt = smem + ((ks & 1) ^ 1) * BUF_B;

    float4 xa, xb;
    if (ks < 31) {
      // issue next W tile -> LDS (async) and next X tile -> regs (T14 split)
#pragma unroll
      for (int i = 0; i < 2; ++i) {
        int s = 2 * w + i;
        long goff = (long)(s * 16 + wgrow) * 1024 + (ks + 1) * 32 + wgcol;
        gload16(Wqk_h + goff, nxt + WH_OFF + s * 1024);
        gload16(Wqk_l + goff, nxt + WL_OFF + s * 1024);
        gload16(Wv_h + goff, nxt + WV_OFF + s * 1024);
      }
      const float* px = x + (mb + xrow) * 1024 + (ks + 1) * 32 + xkc * 8;
      xa = *(const float4*)px;
      xb = *(const float4*)(px + 4);
    }

    // ---- compute from cur ----
    const unsigned short* Xh = (const unsigned short*)(cur + XH_OFF);
    const unsigned short* Xl = (const unsigned short*)(cur + XL_OFF);
    const unsigned short* Wh = (const unsigned short*)(cur + WH_OFF);
    const unsigned short* Wl = (const unsigned short*)(cur + WL_OFF);
    const unsigned short* Wv = (const unsigned short*)(cur + WV_OFF);

    bf16x8 Bh0 = *(const bf16x8*)(Wh + ((2 * w) * 16 + r_lo) * 32 + g * 8);
    bf16x8 Bl0 = *(const bf16x8*)(Wl + ((2 * w) * 16 + r_lo) * 32 + g * 8);
    bf16x8 Bh1 = *(const bf16x8*)(Wh + ((2 * w + 1) * 16 + r_lo) * 32 + g * 8);
    bf16x8 Bl1 = *(const bf16x8*)(Wl + ((2 * w + 1) * 16 + r_lo) * 32 + g * 8);
    bf16x8 Bv0 = *(const bf16x8*)(Wv + (w * 32 + r_lo) * 32 + g * 8);
    bf16x8 Bv1 = *(const bf16x8*)(Wv + (w * 32 + 16 + r_lo) * 32 + g * 8);

#pragma unroll
    for (int rb = 0; rb < 4; ++rb) {
      bf16x8 Ah = *(const bf16x8*)(Xh + (rb * 16 + r_lo) * 32 + g * 8);
      bf16x8 Al = *(const bf16x8*)(Xl + (rb * 16 + r_lo) * 32 + g * 8);
      acc[rb][0] = mfma16(Ah, Bh0, acc[rb][0]);
      acc[rb][0] = mfma16(Al, Bh0, acc[rb][0]);
      acc[rb][0] = mfma16(Ah, Bl0, acc[rb][0]);
      acc[rb][1] = mfma16(Ah, Bh1, acc[rb][1]);
      acc[rb][1] = mfma16(Al, Bh1, acc[rb][1]);
      acc[rb][1] = mfma16(Ah, Bl1, acc[rb][1]);
      acc[rb][2] = mfma16(Ah, Bv0, acc[rb][2]);
      acc[rb][3] = mfma16(Ah, Bv1, acc[rb][3]);
    }

    // ---- late X write into nxt ----
    if (ks < 31) {
      us8 hv, lv;
#pragma unroll
      for (int i = 0; i < 4; ++i) {
        float fa = (i == 0) ? xa.x : (i == 1) ? xa.y : (i == 2) ? xa.z : xa.w;
        float fb = (i == 0) ? xb.x : (i == 1) ? xb.y : (i == 2) ? xb.z : xb.w;
        unsigned short h;
        h = f2bf(fa); hv[i] = h; lv[i] = f2bf(fa - bf2f(h));
        h = f2bf(fb); hv[4 + i] = h; lv[4 + i] = f2bf(fb - bf2f(h));
      }
      *(us8*)(nxt + XH_OFF + xrow * 64 + xkc * 16) = hv;
      *(us8*)(nxt + XL_OFF + xrow * 64 + xkc * 16) = lv;
    }
    __syncthreads();   // drains vmcnt (gload_lds) + lgkmcnt (ds_write) + flips
  }

  // ---- epilogue: qk hi/lo stores (D layout: row=g*4+r, col=r_lo) ----
  {
    float bq0 = bqk[(2 * w) * 16 + r_lo];
    float bq1 = bqk[(2 * w + 1) * 16 + r_lo];
#pragma unroll
    for (int rb = 0; rb < 4; ++rb) {
#pragma unroll
      for (int r = 0; r < 4; ++r) {
        long m = mb + rb * 16 + g * 4 + r;
        int o0 = (2 * w) * 16 + r_lo;
        int o1 = o0 + 16;
        float v0 = acc[rb][0][r] + bq0;
        float v1 = acc[rb][1][r] + bq1;
        unsigned short h0 = f2bf(v0), h1 = f2bf(v1);
        qk_h[m * 128 + o0] = h0;
        qk_l[m * 128 + o0] = f2bf(v0 - bf2f(h0));
        qk_h[m * 128 + o1] = h1;
        qk_l[m * 128 + o1] = f2bf(v1 - bf2f(h1));
      }
    }
  }

  // ---- epilogue: v -> LDS transpose -> vT[b][d][n] coalesced ----
  __syncthreads();
  {
    unsigned short* T = (unsigned short*)smem;       // [128][68]
    float bv0 = bv[w * 32 + r_lo];
    float bv1 = bv[w * 32 + 16 + r_lo];
#pragma unroll
    for (int rb = 0; rb < 4; ++rb) {
#pragma unroll
      for (int r = 0; r < 4; ++r) {
        int n = rb * 16 + g * 4 + r;
        T[(w * 32 + r_lo) * 68 + n] = f2bf(acc[rb][2][r] + bv0);
        T[(w * 32 + 16 + r_lo) * 68 + n] = f2bf(acc[rb][3][r] + bv1);
      }
    }
    __syncthreads();
    const long bb = mb >> 11;        // batch
    const long n0 = mb & 2047;       // n within batch
#pragma unroll
    for (int it = 0; it < 8; ++it) {
      int d = (t >> 4) + 16 * it;
      int m0 = (t & 15) * 4;
      us4 vv = *(const us4*)(T + d * 68 + m0);
      *(us4*)(vT + (bb * 128 + d) * 2048 + n0 + m0) = vv;
    }
  }
}

// ---------------- kernel 3: flash attention (unchanged) ----------------
#define KH_OFF 0
#define KL_OFF 16384
#define VT_OFF 32768
#define P_OFF  49152
#define SMEM_B (49152 + 4 * 2304)

__launch_bounds__(256, 2)
__global__ void kattn(const unsigned short* __restrict__ qk_h,
                      const unsigned short* __restrict__ qk_l,
                      const unsigned short* __restrict__ vT,
                      float* __restrict__ out) {
  __shared__ char smem[SMEM_B];
  const int t = threadIdx.x;
  const int lane = t & 63;
  const int w = t >> 6;
  const int r_lo = lane & 15;
  const int g = lane >> 4;
  const long b = blockIdx.x >> 5;
  const int qt = blockIdx.x & 31;
  const long qrow = b * 2048 + qt * 64 + w * 16 + r_lo;

  bf16x8 Qh[4], Ql[4];
#pragma unroll
  for (int kk = 0; kk < 4; ++kk) {
    Qh[kk] = *(const bf16x8*)(qk_h + qrow * 128 + kk * 32 + g * 8);
    Ql[kk] = *(const bf16x8*)(qk_l + qrow * 128 + kk * 32 + g * 8);
  }

  f32x4 zero = {0.f, 0.f, 0.f, 0.f};
  f32x4 Oa[8];
#pragma unroll
  for (int i = 0; i < 8; ++i) Oa[i] = zero;
  float mrun = -1e30f, lrun = 0.f;

  unsigned short* P = (unsigned short*)(smem + P_OFF + w * 2304);  // per-wave [16][72]

  for (int jt = 0; jt < 32; ++jt) {
    const long jb = b * 2048 + (long)jt * 64;
    const int jn = jt * 64;
    __syncthreads();
#pragma unroll
    for (int c = 0; c < 4; ++c) {
      int slot = w * 4 + c;
      {
        int row = slot * 4 + (lane >> 4);
        int chunk = (lane & 15) ^ (row & 7);
        gload16((const char*)(qk_h + (jb + row) * 128) + chunk * 16,
                smem + KH_OFF + slot * 1024);
        gload16((const char*)(qk_l + (jb + row) * 128) + chunk * 16,
                smem + KL_OFF + slot * 1024);
      }
      {
        int row = slot * 8 + (lane >> 3);
        int chunk = (lane & 7) ^ (row & 7);
        gload16((const char*)(vT + (b * 128 + row) * 2048 + jn) + chunk * 16,
                smem + VT_OFF + slot * 1024);
      }
    }
    asm volatile("s_waitcnt vmcnt(0)" ::: "memory");
    __syncthreads();

    f32x4 sAcc[4];
#pragma unroll
    for (int jc = 0; jc < 4; ++jc) sAcc[jc] = zero;
#pragma unroll
    for (int jc = 0; jc < 4; ++jc) {
      int krow = jc * 16 + r_lo;
#pragma unroll
      for (int kk = 0; kk < 4; ++kk) {
        int chunk = (kk * 4 + g) ^ (krow & 7);
        bf16x8 Kh = *(const bf16x8*)(smem + KH_OFF + krow * 256 + chunk * 16);
        bf16x8 Kl = *(const bf16x8*)(smem + KL_OFF + krow * 256 + chunk * 16);
        sAcc[jc] = mfma16(Kh, Qh[kk], sAcc[jc]);
        sAcc[jc] = mfma16(Kh, Ql[kk], sAcc[jc]);
        sAcc[jc] = mfma16(Kl, Qh[kk], sAcc[jc]);
      }
    }

    float mt = -1e30f;
#pragma unroll
    for (int jc = 0; jc < 4; ++jc)
#pragma unroll
      for (int r = 0; r < 4; ++r) mt = fmaxf(mt, sAcc[jc][r]);
    mt = fmaxf(mt, __shfl_xor(mt, 16));
    mt = fmaxf(mt, __shfl_xor(mt, 32));
    float mnew = fmaxf(mrun, mt);
    float alpha = __expf(mrun - mnew);
    float ls = 0.f;
#pragma unroll
    for (int jc = 0; jc < 4; ++jc) {
      us4 pk;
#pragma unroll
      for (int r = 0; r < 4; ++r) {
        float p = __expf(sAcc[jc][r] - mnew);
        unsigned short pb = f2bf(p);
        pk[r] = pb;
        ls += bf2f(pb);
      }
      *(us4*)(P + r_lo * 72 + jc * 16 + g * 4) = pk;
    }
    ls += __shfl_xor(ls, 16);
    ls += __shfl_xor(ls, 32);
    lrun = lrun * alpha + ls;
    mrun = mnew;
#pragma unroll
    for (int r = 0; r < 4; ++r) {
      float ar = __shfl(alpha, g * 4 + r);
#pragma unroll
      for (int dc = 0; dc < 8; ++dc) Oa[dc][r] *= ar;
    }

#pragma unroll
    for (int ks = 0; ks < 2; ++ks) {
      bf16x8 Pa = *(const bf16x8*)(P + r_lo * 72 + ks * 32 + g * 8);
#pragma unroll
      for (int dc = 0; dc < 8; ++dc) {
        int d = dc * 16 + r_lo;
        int chunk = (ks * 4 + g) ^ (d & 7);
        bf16x8 Vb = *(const bf16x8*)(smem + VT_OFF + d * 128 + chunk * 16);
        Oa[dc] = mfma16(Pa, Vb, Oa[dc]);
      }
    }
  }

#pragma unroll
  for (int r = 0; r < 4; ++r) {
    float li = 1.f / __shfl(lrun, g * 4 + r);
    long orow = b * 2048 + qt * 64 + w * 16 + g * 4 + r;
#pragma unroll
    for (int dc = 0; dc < 8; ++dc) {
      out[orow * 128 + dc * 16 + r_lo] = Oa[dc][r] * li;
    }
  }
}

extern "C" void kernel_launch(void* const* d_in, const int* in_sizes, int n_in,
                              void* d_out, int out_size, void* d_ws, size_t ws_size,
                              hipStream_t stream) {
  const float* x     = (const float*)d_in[0];
  const float* wqk_w = (const float*)d_in[1];
  const float* wqk_b = (const float*)d_in[2];
  const float* wv_w  = (const float*)d_in[3];
  const float* wv_b  = (const float*)d_in[4];
  float* out = (float*)d_out;

  unsigned short* qk_h  = (unsigned short*)d_ws;             // 32768*128
  unsigned short* qk_l  = qk_h + 32768 * 128;
  unsigned short* vT    = qk_l + 32768 * 128;                // [16][128][2048]
  unsigned short* Wqk_h = vT + 16 * 128 * 2048;              // [128][1024]
  unsigned short* Wqk_l = Wqk_h + 128 * 1024;
  unsigned short* Wv_h  = Wqk_l + 128 * 1024;

  hipLaunchKernelGGL(kprep, dim3(512), dim3(256), 0, stream,
                     wqk_w, wv_w, Wqk_h, Wqk_l, Wv_h);
  hipLaunchKernelGGL(kproj, dim3(512), dim3(256), 2 * BUF_B, stream,
                     x, Wqk_h, Wqk_l, Wv_h, wqk_b, wv_b, qk_h, qk_l, vT);
  hipLaunchKernelGGL(kattn, dim3(512), dim3(256), 0, stream,
                     qk_h, qk_l, vT, out);
}

// Round 3
// 103.729 us; speedup vs baseline: 3.2266x; 1.3947x over previous
//
#include <hip/hip_runtime.h>
#include <hip/hip_bf16.h>

// Problem: x[16,2048,1024] f32; qk = x@Wqk^T + bqk; v = x@Wv^T + bv (D=128)
// out = softmax(qk@qk^T) @ v   -> [16,2048,128] f32
//
// Precision plan: softmax is ~argmax onto the diagonal (s_ii=|qk|^2 ~ 43 vs
// off-diag ~ 12), so plain bf16 everywhere suffices; error is dominated by
// bf16(v) + P rounding (~0.016 absmax, threshold 0.068).
//
// ws layout (shorts): qk_h 4M | vT 4M | Wqk_h 128K | Wv_h 128K

typedef __bf16 bf16x8 __attribute__((ext_vector_type(8)));
typedef float f32x4 __attribute__((ext_vector_type(4)));
typedef unsigned short us4 __attribute__((ext_vector_type(4)));
typedef unsigned short us8 __attribute__((ext_vector_type(8)));

static __device__ __forceinline__ unsigned short f2bf(float f) {
  unsigned u = __builtin_bit_cast(unsigned, f);
  u += 0x7fffu + ((u >> 16) & 1u);          // RNE
  return (unsigned short)(u >> 16);
}
static __device__ __forceinline__ float bf2f(unsigned short h) {
  unsigned u = ((unsigned)h) << 16;
  return __builtin_bit_cast(float, u);
}
static __device__ __forceinline__ f32x4 mfma16(bf16x8 a, bf16x8 b, f32x4 c) {
  return __builtin_amdgcn_mfma_f32_16x16x32_bf16(a, b, c, 0, 0, 0);
}
static __device__ __forceinline__ void gload16(const void* g, void* l) {
  __builtin_amdgcn_global_load_lds(
      (const __attribute__((address_space(1))) unsigned*)g,
      (__attribute__((address_space(3))) unsigned*)l, 16, 0, 0);
}

// ---------------- kernel 1: weight prep (fp32 -> bf16) ----------------
__global__ void kprep(const float* __restrict__ wqk, const float* __restrict__ wv,
                      unsigned short* __restrict__ Wqk_h, unsigned short* __restrict__ Wv_h) {
  int i = blockIdx.x * 256 + threadIdx.x;   // grid covers exactly 128*1024
  Wqk_h[i] = f2bf(wqk[i]);
  Wv_h[i] = f2bf(wv[i]);
}

// ---------------- kernel 2: projections (bf16, dbuf, counted vmcnt) ---------
// block = 64 rows, 4 waves column-partitioned. LDS buffer (20 KB):
// Xh [64][32] @0 | Wh [32 slots.. 2 per wave][32] @4096 | Wv @12288
#define XH_OFF 0
#define WH_OFF 4096
#define WV_OFF 12288
#define PBUF_B 20480

__launch_bounds__(256, 4)
__global__ void kproj(const float* __restrict__ x,
                      const unsigned short* __restrict__ Wqk_h,
                      const unsigned short* __restrict__ Wv_h,
                      const float* __restrict__ bqk, const float* __restrict__ bv,
                      unsigned short* __restrict__ qk_h,
                      unsigned short* __restrict__ vT) {
  extern __shared__ char smem[];            // 2 * PBUF_B = 40 KB (dynamic)
  const int t = threadIdx.x;
  const int lane = t & 63;
  const int w = t >> 6;
  const int r_lo = lane & 15;
  const int g = lane >> 4;
  const long mb = (long)blockIdx.x * 64;

  const int xrow = t >> 2;                  // X staging: row, 8-k chunk
  const int xkc = t & 3;
  const int wgrow = (lane >> 2);            // W staging: row in 16-row slot
  const int wgcol = (lane & 3) * 8;         // k offset (shorts)

  f32x4 zero = {0.f, 0.f, 0.f, 0.f};
  f32x4 acc[4][4];                          // [rowblock][qk0,qk1,v0,v1]
#pragma unroll
  for (int i = 0; i < 4; ++i)
#pragma unroll
    for (int j = 0; j < 4; ++j) acc[i][j] = zero;

  // ---- prologue: X(0) regs, W(0) gloads -> buf0, convert+write X(0) ----
  {
    const float* px = x + (mb + xrow) * 1024 + xkc * 8;
    float4 xa = *(const float4*)px;
    float4 xb = *(const float4*)(px + 4);
#pragma unroll
    for (int i = 0; i < 2; ++i) {
      int s = 2 * w + i;
      long goff = (long)(s * 16 + wgrow) * 1024 + wgcol;
      gload16(Wqk_h + goff, smem + WH_OFF + s * 1024);
      gload16(Wv_h + goff, smem + WV_OFF + s * 1024);
    }
    us8 hv;
#pragma unroll
    for (int i = 0; i < 4; ++i) {
      float fa = (i == 0) ? xa.x : (i == 1) ? xa.y : (i == 2) ? xa.z : xa.w;
      float fb = (i == 0) ? xb.x : (i == 1) ? xb.y : (i == 2) ? xb.z : xb.w;
      hv[i] = f2bf(fa);
      hv[4 + i] = f2bf(fb);
    }
    *(us8*)(smem + XH_OFF + xrow * 64 + xkc * 16) = hv;
  }

  // ---- main loop ----
  for (int ks = 0; ks < 32; ++ks) {
    char* cur = smem + (ks & 1) * PBUF_B;
    char* nxt = smem + ((ks & 1) ^ 1) * PBUF_B;

    float4 xa, xb;
    if (ks < 31) {
      const float* px = x + (mb + xrow) * 1024 + (ks + 1) * 32 + xkc * 8;
      xa = *(const float4*)px;              // X first: its use waits vmcnt(4)
      xb = *(const float4*)(px + 4);
#pragma unroll
      for (int i = 0; i < 2; ++i) {
        int s = 2 * w + i;
        long goff = (long)(s * 16 + wgrow) * 1024 + (ks + 1) * 32 + wgcol;
        gload16(Wqk_h + goff, nxt + WH_OFF + s * 1024);
        gload16(Wv_h + goff, nxt + WV_OFF + s * 1024);
      }
      asm volatile("s_waitcnt vmcnt(6) lgkmcnt(0)" ::: "memory");
    } else {
      asm volatile("s_waitcnt vmcnt(0) lgkmcnt(0)" ::: "memory");
    }
    __builtin_amdgcn_s_barrier();

    const unsigned short* Xh = (const unsigned short*)(cur + XH_OFF);
    const unsigned short* Wh = (const unsigned short*)(cur + WH_OFF);
    const unsigned short* Wv = (const unsigned short*)(cur + WV_OFF);

    bf16x8 Bh0 = *(const bf16x8*)(Wh + ((2 * w) * 16 + r_lo) * 32 + g * 8);
    bf16x8 Bh1 = *(const bf16x8*)(Wh + ((2 * w + 1) * 16 + r_lo) * 32 + g * 8);
    bf16x8 Bv0 = *(const bf16x8*)(Wv + (w * 32 + r_lo) * 32 + g * 8);
    bf16x8 Bv1 = *(const bf16x8*)(Wv + (w * 32 + 16 + r_lo) * 32 + g * 8);

    __builtin_amdgcn_s_setprio(1);
#pragma unroll
    for (int rb = 0; rb < 4; ++rb) {
      bf16x8 Ah = *(const bf16x8*)(Xh + (rb * 16 + r_lo) * 32 + g * 8);
      acc[rb][0] = mfma16(Ah, Bh0, acc[rb][0]);
      acc[rb][1] = mfma16(Ah, Bh1, acc[rb][1]);
      acc[rb][2] = mfma16(Ah, Bv0, acc[rb][2]);
      acc[rb][3] = mfma16(Ah, Bv1, acc[rb][3]);
    }
    __builtin_amdgcn_s_setprio(0);

    if (ks < 31) {
      us8 hv;
#pragma unroll
      for (int i = 0; i < 4; ++i) {
        float fa = (i == 0) ? xa.x : (i == 1) ? xa.y : (i == 2) ? xa.z : xa.w;
        float fb = (i == 0) ? xb.x : (i == 1) ? xb.y : (i == 2) ? xb.z : xb.w;
        hv[i] = f2bf(fa);
        hv[4 + i] = f2bf(fb);
      }
      *(us8*)(nxt + XH_OFF + xrow * 64 + xkc * 16) = hv;
    }
    __builtin_amdgcn_s_barrier();
  }

  // ---- epilogue: qk store (D layout: row=g*4+r, col=r_lo) ----
  {
    float bq0 = bqk[(2 * w) * 16 + r_lo];
    float bq1 = bqk[(2 * w + 1) * 16 + r_lo];
#pragma unroll
    for (int rb = 0; rb < 4; ++rb) {
#pragma unroll
      for (int r = 0; r < 4; ++r) {
        long m = mb + rb * 16 + g * 4 + r;
        int o0 = (2 * w) * 16 + r_lo;
        qk_h[m * 128 + o0] = f2bf(acc[rb][0][r] + bq0);
        qk_h[m * 128 + o0 + 16] = f2bf(acc[rb][1][r] + bq1);
      }
    }
  }

  // ---- epilogue: v -> LDS transpose -> vT[b][d][n] coalesced ----
  __syncthreads();
  {
    unsigned short* T = (unsigned short*)smem;       // [128][68]
    float bv0 = bv[w * 32 + r_lo];
    float bv1 = bv[w * 32 + 16 + r_lo];
#pragma unroll
    for (int rb = 0; rb < 4; ++rb) {
#pragma unroll
      for (int r = 0; r < 4; ++r) {
        int n = rb * 16 + g * 4 + r;
        T[(w * 32 + r_lo) * 68 + n] = f2bf(acc[rb][2][r] + bv0);
        T[(w * 32 + 16 + r_lo) * 68 + n] = f2bf(acc[rb][3][r] + bv1);
      }
    }
    __syncthreads();
    const long bb = mb >> 11;        // batch
    const long n0 = mb & 2047;       // n within batch
#pragma unroll
    for (int it = 0; it < 8; ++it) {
      int d = (t >> 4) + 16 * it;
      int m0 = (t & 15) * 4;
      us4 vv = *(const us4*)(T + d * 68 + m0);
      *(us4*)(vT + (bb * 128 + d) * 2048 + n0 + m0) = vv;
    }
  }
}

// ---------------- kernel 3: flash attention (dbuf, counted vmcnt) -----------
// block = 64 q rows of one batch, 4 waves x 16 q rows; KV tiles of 64.
// LDS: K dbuf 2x16K @0 | V dbuf 2x16K @32768 | P 4x2304 @65536 -> 74752 B
#define AK_OFF 0
#define AV_OFF 32768
#define AP_OFF 65536
#define ASMEM_B 74752

__launch_bounds__(256, 2)
__global__ void kattn(const unsigned short* __restrict__ qk_h,
                      const unsigned short* __restrict__ vT,
                      float* __restrict__ out) {
  __shared__ char smem[ASMEM_B];
  const int t = threadIdx.x;
  const int lane = t & 63;
  const int w = t >> 6;
  const int r_lo = lane & 15;
  const int g = lane >> 4;
  const long b = blockIdx.x >> 5;
  const int qt = blockIdx.x & 31;
  const long qrow = b * 2048 + qt * 64 + w * 16 + r_lo;

  // Q fragments; pin materialization BEFORE the loop so the compiler's
  // vmcnt wait for them doesn't land inside the pipelined loop.
  f32x4 Qm[4];
#pragma unroll
  for (int kk = 0; kk < 4; ++kk)
    Qm[kk] = *(const f32x4*)(qk_h + qrow * 128 + kk * 32 + g * 8);
#pragma unroll
  for (int kk = 0; kk < 4; ++kk)
    asm volatile("" : "+v"(Qm[kk]));

  f32x4 zero = {0.f, 0.f, 0.f, 0.f};
  f32x4 Oa[8];
#pragma unroll
  for (int i = 0; i < 8; ++i) Oa[i] = zero;
  float mrun = -1e30f, lrun = 0.f;

  unsigned short* P = (unsigned short*)(smem + AP_OFF + w * 2304);  // [16][72]

  // ---- prologue: stage tile 0 into buf0 (8 gload16 per thread) ----
  {
    const long jb = b * 2048;
#pragma unroll
    for (int c = 0; c < 4; ++c) {
      int slot = w * 4 + c;
      int row = slot * 4 + (lane >> 4);
      int chunk = (lane & 15) ^ (row & 7);
      gload16((const char*)(qk_h + (jb + row) * 128) + chunk * 16,
              smem + AK_OFF + slot * 1024);
      int rowd = slot * 8 + (lane >> 3);
      int chv = (lane & 7) ^ (rowd & 7);
      gload16((const char*)(vT + (b * 128 + rowd) * 2048) + chv * 16,
              smem + AV_OFF + slot * 1024);
    }
  }

  for (int jt = 0; jt < 32; ++jt) {
    const int cb = jt & 1;
    if (jt < 31) {
      // stage tile jt+1 into the other buffer (8 gload16)
      const long jb = b * 2048 + (long)(jt + 1) * 64;
      const int jn = (jt + 1) * 64;
      char* Kd = smem + AK_OFF + (cb ^ 1) * 16384;
      char* Vd = smem + AV_OFF + (cb ^ 1) * 16384;
#pragma unroll
      for (int c = 0; c < 4; ++c) {
        int slot = w * 4 + c;
        int row = slot * 4 + (lane >> 4);
        int chunk = (lane & 15) ^ (row & 7);
        gload16((const char*)(qk_h + (jb + row) * 128) + chunk * 16,
                Kd + slot * 1024);
        int rowd = slot * 8 + (lane >> 3);
        int chv = (lane & 7) ^ (rowd & 7);
        gload16((const char*)(vT + (b * 128 + rowd) * 2048 + jn) + chv * 16,
                Vd + slot * 1024);
      }
      asm volatile("s_waitcnt vmcnt(8)" ::: "memory");   // tile jt landed
    } else {
      asm volatile("s_waitcnt vmcnt(0)" ::: "memory");
    }
    __builtin_amdgcn_s_barrier();

    const char* Kb = smem + AK_OFF + cb * 16384;
    const char* Vb = smem + AV_OFF + cb * 16384;

    // ---- S^T[j][q] = K . Q^T ----
    f32x4 sAcc[4];
#pragma unroll
    for (int jc = 0; jc < 4; ++jc) sAcc[jc] = zero;
    __builtin_amdgcn_s_setprio(1);
#pragma unroll
    for (int jc = 0; jc < 4; ++jc) {
      int krow = jc * 16 + r_lo;
#pragma unroll
      for (int kk = 0; kk < 4; ++kk) {
        int chunk = (kk * 4 + g) ^ (krow & 7);
        bf16x8 Kh = *(const bf16x8*)(Kb + krow * 256 + chunk * 16);
        sAcc[jc] = mfma16(Kh, __builtin_bit_cast(bf16x8, Qm[kk]), sAcc[jc]);
      }
    }
    __builtin_amdgcn_s_setprio(0);

    // ---- online softmax (defer-max THR=8; tile-skip at -15) ----
    float mt = -1e30f;
#pragma unroll
    for (int jc = 0; jc < 4; ++jc)
#pragma unroll
      for (int r = 0; r < 4; ++r) mt = fmaxf(mt, sAcc[jc][r]);
    mt = fmaxf(mt, __shfl_xor(mt, 16));
    mt = fmaxf(mt, __shfl_xor(mt, 32));

    if (__any(mt > mrun - 15.f)) {         // tile contributes (bound: 64*e^-15)
      if (__any(mt > mrun + 8.f)) {        // T13: rescale only on real growth
        float mnew = fmaxf(mrun, mt);
        float alpha = __expf(mrun - mnew);
        lrun *= alpha;
#pragma unroll
        for (int r = 0; r < 4; ++r) {
          float ar = __shfl(alpha, g * 4 + r);
#pragma unroll
          for (int dc = 0; dc < 8; ++dc) Oa[dc][r] *= ar;
        }
        mrun = mnew;
      }
      float ls = 0.f;
#pragma unroll
      for (int jc = 0; jc < 4; ++jc) {
        us4 pk;
#pragma unroll
        for (int r = 0; r < 4; ++r) {
          float p = __expf(sAcc[jc][r] - mrun);   // bounded by e^8
          pk[r] = f2bf(p);
          ls += bf2f(pk[r]);                       // denom consistent w/ numer
        }
        *(us4*)(P + r_lo * 72 + jc * 16 + g * 4) = pk;
      }
      ls += __shfl_xor(ls, 16);
      ls += __shfl_xor(ls, 32);
      lrun += ls;

      // ---- PV: O[q][d] += P[q][j] * V[j][d] ----
      __builtin_amdgcn_s_setprio(1);
#pragma unroll
      for (int ks = 0; ks < 2; ++ks) {
        bf16x8 Pa = *(const bf16x8*)(P + r_lo * 72 + ks * 32 + g * 8);
#pragma unroll
        for (int dc = 0; dc < 8; ++dc) {
          int d = dc * 16 + r_lo;
          int chunk = (ks * 4 + g) ^ (d & 7);
          bf16x8 Vb8 = *(const bf16x8*)(Vb + d * 128 + chunk * 16);
          Oa[dc] = mfma16(Pa, Vb8, Oa[dc]);
        }
      }
      __builtin_amdgcn_s_setprio(0);
    }
    __builtin_amdgcn_s_barrier();
  }

  // ---- epilogue: normalize and store fp32 ----
#pragma unroll
  for (int r = 0; r < 4; ++r) {
    float li = 1.f / __shfl(lrun, g * 4 + r);
    long orow = b * 2048 + qt * 64 + w * 16 + g * 4 + r;
#pragma unroll
    for (int dc = 0; dc < 8; ++dc) {
      out[orow * 128 + dc * 16 + r_lo] = Oa[dc][r] * li;
    }
  }
}

extern "C" void kernel_launch(void* const* d_in, const int* in_sizes, int n_in,
                              void* d_out, int out_size, void* d_ws, size_t ws_size,
                              hipStream_t stream) {
  const float* x     = (const float*)d_in[0];
  const float* wqk_w = (const float*)d_in[1];
  const float* wqk_b = (const float*)d_in[2];
  const float* wv_w  = (const float*)d_in[3];
  const float* wv_b  = (const float*)d_in[4];
  float* out = (float*)d_out;

  unsigned short* qk_h  = (unsigned short*)d_ws;             // 32768*128
  unsigned short* vT    = qk_h + 32768 * 128;                // [16][128][2048]
  unsigned short* Wqk_h = vT + 16 * 128 * 2048;              // [128][1024]
  unsigned short* Wv_h  = Wqk_h + 128 * 1024;

  hipLaunchKernelGGL(kprep, dim3(512), dim3(256), 0, stream,
                     wqk_w, wv_w, Wqk_h, Wv_h);
  hipLaunchKernelGGL(kproj, dim3(512), dim3(256), 2 * PBUF_B, stream,
                     x, Wqk_h, Wv_h, wqk_b, wv_b, qk_h, vT);
  hipLaunchKernelGGL(kattn, dim3(512), dim3(256), 0, stream,
                     qk_h, vT, out);
}